// Round 6
// baseline (342.480 us; speedup 1.0000x reference)
//
#include <hip/hip_runtime.h>
#include <math.h>
#include <stdint.h>

#define POS_W 1.0f
#define ANG_W 1.0f
#define WID_W 1.0f

__device__ __forceinline__ float smooth_l1(float x) {
    float a = fabsf(x);
    return a < 1.0f ? 0.5f * x * x : a - 0.5f;
}

// ---------------------------------------------------------------------------
// Kernel A: per-block (256 counts) sums. blockSums is 16 KB; kernel B derives
// each block's exclusive prefix from it out of L2/LLC.
// ---------------------------------------------------------------------------
__global__ void k_block_sums(const int* __restrict__ counts, int stride, int n,
                             int* __restrict__ blockSums) {
    int i = blockIdx.x * 256 + threadIdx.x;
    int c = (i < n) ? counts[(long long)i * stride] : 0;
    for (int off = 32; off > 0; off >>= 1) c += __shfl_down(c, off, 64);
    __shared__ int sdata[4];
    int lane = threadIdx.x & 63, wave = threadIdx.x >> 6;
    if (lane == 0) sdata[wave] = c;
    __syncthreads();
    if (threadIdx.x == 0)
        blockSums[blockIdx.x] = sdata[0] + sdata[1] + sdata[2] + sdata[3];
}

// ---------------------------------------------------------------------------
// Kernel B: one thread per prediction. NO LDS staging of targets: windows are
// disjoint (each GT row consumed by exactly one thread), so LDS buys no
// reuse; wave-level spatial locality (contiguous sub-windows, ~2.7 rows per
// 64 B line) gives coalescing through L1/L2 for free. Each thread streams its
// own c rows with a depth-2 software pipeline. 48 B LDS -> 8 blocks/CU, 32
// waves/CU; TLP hides load latency. Zero barriers after the prefix scan.
// ---------------------------------------------------------------------------
__global__ __launch_bounds__(256) void k_loss(
    const float* __restrict__ pred, const float* __restrict__ tgt,
    const int* __restrict__ counts, int stride, int n,
    const int* __restrict__ blockSums, float invN, float* __restrict__ out) {
    __shared__ int wsum[4];
    __shared__ int wpre[4];
    __shared__ float fs[4];

    int t = threadIdx.x;
    int lane = t & 63, wave = t >> 6;
    int b = blockIdx.x;
    int i = b * 256 + t;
    int c = (i < n) ? counts[(long long)i * stride] : 0;

    // per-thread partial of exclusive block prefix: sum blockSums[0..b)
    int pre = 0;
    for (int j = t; j < b; j += 256) pre += blockSums[j];

    // wave-level inclusive scan of counts (no barriers)
    int incl = c;
#pragma unroll
    for (int d = 1; d < 64; d <<= 1) {
        int v = __shfl_up(incl, d, 64);
        if (lane >= d) incl += v;
    }
    for (int o = 32; o > 0; o >>= 1) pre += __shfl_down(pre, o, 64);
    if (lane == 63) wsum[wave] = incl;
    if (lane == 0) wpre[wave] = pre;

    // pred loads: issue early; latency hides under the scan barrier
    bool active = (i < n) && (c > 0);
    float p0 = 0, p1 = 0, p2 = 0, p3 = 0, p4 = 0;
    if (active) {
        const float2* p2p = (const float2*)(pred + (long long)i * 6);
        float2 a = p2p[0], bb = p2p[1], w = p2p[2];
        p0 = a.x; p1 = a.y; p2 = bb.x; p3 = bb.y; p4 = w.x;
    }
    __syncthreads();

    int w0 = wsum[0], w1 = wsum[1], w2 = wsum[2], w3 = wsum[3];
    int waveOff = (wave > 0 ? w0 : 0) + (wave > 1 ? w1 : 0) + (wave > 2 ? w2 : 0);
    int off = waveOff + incl - c;       // exclusive prefix within block
    int winStart = wpre[0] + wpre[1] + wpre[2] + wpre[3];

    float best = INFINITY;
    float b0 = 0, b1 = 0, b2 = 0, b3 = 0, b4 = 0;

    if (active) {
        // this thread's private contiguous GT slice: rows gr .. gr+c-1
        const float2* rp =
            (const float2*)tgt + (long long)(winStart + off) * 3;
        // depth-2 software pipeline: next row's loads in flight during the
        // current row's compare (load-to-use distance ~1 full iteration)
        float2 ga = rp[0], gb = rp[1], gw = rp[2];
        for (int rr = 0; rr < c; ++rr) {
            float2 na, nb, nw;
            if (rr + 1 < c) {
                int q = (rr + 1) * 3;
                na = rp[q]; nb = rp[q + 1]; nw = rp[q + 2];
            }
            float d0 = p0 - ga.x, d1 = p1 - ga.y;
            float d2 = p2 - gb.x, d3 = p3 - gb.y;
            float d4 = p4 - gw.x;
            float dist = POS_W * (d0 * d0 + d1 * d1) +
                         ANG_W * (d2 * d2 + d3 * d3) + WID_W * d4 * d4;
            if (dist < best) {  // strict <: first occurrence, matches ref
                best = dist;
                b0 = ga.x; b1 = ga.y; b2 = gb.x; b3 = gb.y; b4 = gw.x;
            }
            ga = na; gb = nb; gw = nw;
        }
    }

    float loss = 0.0f;
    if (active) {
        loss = POS_W * (smooth_l1(p0 - b0) + smooth_l1(p1 - b1)) +
               ANG_W * (fabsf(p2 - b2) + fabsf(p3 - b3)) +
               WID_W * smooth_l1(p4 - b4);
    }

    for (int o = 32; o > 0; o >>= 1) loss += __shfl_down(loss, o, 64);
    if (lane == 0) fs[wave] = loss;
    __syncthreads();
    if (t == 0) {
        float tot = (fs[0] + fs[1] + fs[2] + fs[3]) * invN;
        atomicAdd(out, tot);
    }
}

// ---------------------------------------------------------------------------
extern "C" void kernel_launch(void* const* d_in, const int* in_sizes, int n_in,
                              void* d_out, int out_size, void* d_ws,
                              size_t ws_size, hipStream_t stream) {
    const float* pred = (const float*)d_in[0];
    const float* tgt = (const float*)d_in[1];
    const int* counts = (const int*)d_in[2];
    int n = in_sizes[0] / 6;
    int stride = (in_sizes[2] == n) ? 1 : 2;  // int64 counts -> read low words
    int nb = (n + 255) / 256;

    int* blockSums = (int*)d_ws;
    float* out = (float*)d_out;

    hipMemsetAsync(d_out, 0, sizeof(float), stream);
    k_block_sums<<<nb, 256, 0, stream>>>(counts, stride, n, blockSums);
    k_loss<<<nb, 256, 0, stream>>>(pred, tgt, counts, stride, n, blockSums,
                                   1.0f / n, out);
}

// Round 7
// 299.703 us; speedup vs baseline: 1.1427x; 1.1427x over previous
//
#include <hip/hip_runtime.h>
#include <math.h>
#include <stdint.h>

#define POS_W 1.0f
#define ANG_W 1.0f
#define WID_W 1.0f
#define SEGS_A 28        // first-half segments (7 per wave)
#define SEGS_B 24        // second-half segments (6 per wave)
#define SEGS_T (SEGS_A + SEGS_B)   // 52 x 1KB = 52 KB buffer
#define ROWS_A 1194      // rows fully contained in segs [0,SEGS_A) (both sh)
#define ROWS_PASS 2112   // rows per staging pass (even; capacity 2217)

__device__ __forceinline__ float smooth_l1(float x) {
    float a = fabsf(x);
    return a < 1.0f ? 0.5f * x * x : a - 0.5f;
}

// direct HBM->LDS DMA, 16 B/lane, no VGPR staging (nothing to spill).
__device__ __forceinline__ void gl_lds16(const float4* g, float4* l) {
    __builtin_amdgcn_global_load_lds(
        (const __attribute__((address_space(1))) void*)g,
        (__attribute__((address_space(3))) void*)l, 16, 0, 0);
}

// ---------------------------------------------------------------------------
// Kernel A: per-block (256 counts) sums. blockSums is 16 KB; kernel B derives
// each block's exclusive prefix from it out of L2/LLC.
// ---------------------------------------------------------------------------
__global__ void k_block_sums(const int* __restrict__ counts, int stride, int n,
                             int* __restrict__ blockSums) {
    int i = blockIdx.x * 256 + threadIdx.x;
    int c = (i < n) ? counts[(long long)i * stride] : 0;
    for (int off = 32; off > 0; off >>= 1) c += __shfl_down(c, off, 64);
    __shared__ int sdata[4];
    int lane = threadIdx.x & 63, wave = threadIdx.x >> 6;
    if (lane == 0) sdata[wave] = c;
    __syncthreads();
    if (threadIdx.x == 0)
        blockSums[blockIdx.x] = sdata[0] + sdata[1] + sdata[2] + sdata[3];
}

// ---------------------------------------------------------------------------
// Kernel B: one thread per prediction. Block window staged via global_load_lds
// in ONE padded volley (13 segs/wave exactly), half-split counted vmcnt:
// s_waitcnt vmcnt(6) -> compute rows < ROWS_A while the B-half (~25 KB) stays
// in flight; vmcnt(0) -> compute the rest. blockSums prefix unrolled into 4
// independent accumulators (batched L2 loads, no serial load-add chain).
// ---------------------------------------------------------------------------
__global__ __launch_bounds__(256) void k_loss(
    const float* __restrict__ pred, const float* __restrict__ tgt,
    const int* __restrict__ counts, int stride, int n, int mrows,
    const int* __restrict__ blockSums, float invN, float* __restrict__ out) {
    __shared__ float4 buf[SEGS_T * 64];  // 52 KB -> 3 blocks/CU
    __shared__ int wsum[4];
    __shared__ int wpre[4];
    __shared__ float fs[4];

    int t = threadIdx.x;
    int lane = t & 63, wave = t >> 6;
    int b = blockIdx.x;
    int i = b * 256 + t;
    int c = (i < n) ? counts[(long long)i * stride] : 0;

    // exclusive block prefix: sum blockSums[0..b), 4 independent accumulators
    int pre;
    {
        int s0 = 0, s1 = 0, s2 = 0, s3 = 0;
        int j = t;
        for (; j + 768 < b; j += 1024) {
            s0 += blockSums[j];       s1 += blockSums[j + 256];
            s2 += blockSums[j + 512]; s3 += blockSums[j + 768];
        }
        for (; j < b; j += 256) s0 += blockSums[j];
        pre = (s0 + s1) + (s2 + s3);
    }

    // wave-level inclusive scan of counts (no barriers)
    int incl = c;
#pragma unroll
    for (int d = 1; d < 64; d <<= 1) {
        int v = __shfl_up(incl, d, 64);
        if (lane >= d) incl += v;
    }
    for (int o = 32; o > 0; o >>= 1) pre += __shfl_down(pre, o, 64);
    if (lane == 63) wsum[wave] = incl;
    if (lane == 0) wpre[wave] = pre;

    // pred loads: issue early; latency hides under the scan barrier
    bool active = (i < n) && (c > 0);
    float p0 = 0, p1 = 0, p2 = 0, p3 = 0, p4 = 0;
    if (active) {
        const float2* p2p = (const float2*)(pred + (long long)i * 6);
        float2 a = p2p[0], bb = p2p[1], w = p2p[2];
        p0 = a.x; p1 = a.y; p2 = bb.x; p3 = bb.y; p4 = w.x;
    }
    __syncthreads();   // drains all prior VMEM: DMA vmcnt counts start exact

    int w0 = wsum[0], w1 = wsum[1], w2 = wsum[2], w3 = wsum[3];
    int waveOff = (wave > 0 ? w0 : 0) + (wave > 1 ? w1 : 0) + (wave > 2 ? w2 : 0);
    int off = waveOff + incl - c;       // exclusive prefix within block
    int total = w0 + w1 + w2 + w3;      // rows this block consumes
    int winStart = wpre[0] + wpre[1] + wpre[2] + wpre[3];

    // window geometry: align start down to 16 B; sh=1 if start is 8 B into f4
    long long winB = (long long)winStart * 24;
    long long base4 = (winB & ~15ll) >> 4;      // absolute f4 idx of window
    int sh = (int)(winStart & 1);
    long long f4last = (((long long)mrows * 24) >> 4) - 1;  // last valid f4
    const float4* tgt4 = (const float4*)tgt;
    const float2* ch2 = (const float2*)buf;

    float best = INFINITY;
    float b0 = 0, b1 = 0, b2 = 0, b3 = 0, b4 = 0;

    if (total > 0) {  // block-uniform: barriers inside are uniform
        for (int base = 0; base < total; base += ROWS_PASS) {
            int rows = min(ROWS_PASS, total - base);
            long long q0 = base4 + (((long long)base * 3) >> 1);  // base even
            // padded volley: every wave issues exactly 7 A-segs + 6 B-segs
#pragma unroll
            for (int k = 0; k < 7; ++k) {
                int seg = wave + 4 * k;                  // segs 0..27
                long long gi = q0 + (long long)(seg << 6) + lane;
                if (gi > f4last) gi = f4last;            // clamp: no OOB
                gl_lds16(tgt4 + gi, &buf[seg * 64]);
            }
#pragma unroll
            for (int k = 0; k < 6; ++k) {
                int seg = SEGS_A + wave + 4 * k;         // segs 28..51
                long long gi = q0 + (long long)(seg << 6) + lane;
                if (gi > f4last) gi = f4last;
                gl_lds16(tgt4 + gi, &buf[seg * 64]);
            }
            // A-half landed (7 oldest of this wave's 13); B stays in flight
            asm volatile("s_waitcnt vmcnt(6)" ::: "memory");
            __builtin_amdgcn_s_barrier();
            __builtin_amdgcn_sched_barrier(0);

            int rowsA = min(rows, ROWS_A);
            if (active) {
                int lo = max(off, base), hi = min(off + c, base + rowsA);
                for (int rr = lo; rr < hi; ++rr) {
                    int l2i = (rr - base) * 3 + sh;
                    float2 ga = ch2[l2i], gb = ch2[l2i + 1], gw = ch2[l2i + 2];
                    float d0 = p0 - ga.x, d1 = p1 - ga.y;
                    float d2 = p2 - gb.x, d3 = p3 - gb.y;
                    float d4 = p4 - gw.x;
                    float dist = POS_W * (d0 * d0 + d1 * d1) +
                                 ANG_W * (d2 * d2 + d3 * d3) + WID_W * d4 * d4;
                    if (dist < best) {  // strict <: first occurrence
                        best = dist;
                        b0 = ga.x; b1 = ga.y; b2 = gb.x; b3 = gb.y; b4 = gw.x;
                    }
                }
            }
            // B-half landed
            asm volatile("s_waitcnt vmcnt(0)" ::: "memory");
            __builtin_amdgcn_s_barrier();
            __builtin_amdgcn_sched_barrier(0);

            if (active && rows > ROWS_A) {
                int lo = max(off, base + ROWS_A);
                int hi = min(off + c, base + rows);
                for (int rr = lo; rr < hi; ++rr) {
                    int l2i = (rr - base) * 3 + sh;
                    float2 ga = ch2[l2i], gb = ch2[l2i + 1], gw = ch2[l2i + 2];
                    float d0 = p0 - ga.x, d1 = p1 - ga.y;
                    float d2 = p2 - gb.x, d3 = p3 - gb.y;
                    float d4 = p4 - gw.x;
                    float dist = POS_W * (d0 * d0 + d1 * d1) +
                                 ANG_W * (d2 * d2 + d3 * d3) + WID_W * d4 * d4;
                    if (dist < best) {
                        best = dist;
                        b0 = ga.x; b1 = ga.y; b2 = gb.x; b3 = gb.y; b4 = gw.x;
                    }
                }
            }
            if (base + ROWS_PASS < total) {  // generic multi-pass only
                asm volatile("s_waitcnt lgkmcnt(0)" ::: "memory");
                __builtin_amdgcn_s_barrier();
                __builtin_amdgcn_sched_barrier(0);
            }
        }
    }

    float loss = 0.0f;
    if (active) {
        loss = POS_W * (smooth_l1(p0 - b0) + smooth_l1(p1 - b1)) +
               ANG_W * (fabsf(p2 - b2) + fabsf(p3 - b3)) +
               WID_W * smooth_l1(p4 - b4);
    }

    for (int o = 32; o > 0; o >>= 1) loss += __shfl_down(loss, o, 64);
    if (lane == 0) fs[wave] = loss;
    __syncthreads();
    if (t == 0) {
        float tot = (fs[0] + fs[1] + fs[2] + fs[3]) * invN;
        atomicAdd(out, tot);
    }
}

// ---------------------------------------------------------------------------
extern "C" void kernel_launch(void* const* d_in, const int* in_sizes, int n_in,
                              void* d_out, int out_size, void* d_ws,
                              size_t ws_size, hipStream_t stream) {
    const float* pred = (const float*)d_in[0];
    const float* tgt = (const float*)d_in[1];
    const int* counts = (const int*)d_in[2];
    int n = in_sizes[0] / 6;
    int mrows = in_sizes[1] / 6;
    int stride = (in_sizes[2] == n) ? 1 : 2;  // int64 counts -> read low words
    int nb = (n + 255) / 256;

    int* blockSums = (int*)d_ws;
    float* out = (float*)d_out;

    hipMemsetAsync(d_out, 0, sizeof(float), stream);
    k_block_sums<<<nb, 256, 0, stream>>>(counts, stride, n, blockSums);
    k_loss<<<nb, 256, 0, stream>>>(pred, tgt, counts, stride, n, mrows,
                                   blockSums, 1.0f / n, out);
}